// Round 8
// baseline (528.251 us; speedup 1.0000x reference)
//
#include <hip/hip_runtime.h>

#define NLVL 16
#define NTOT 1846083
#define NTILE 4376
#define NBLOCK 1094   // 4 wave-tiles per block
#define INBYTES 236298624   // 2*NTOT*16*4

typedef float  f32x4  __attribute__((ext_vector_type(4)));
typedef __bf16 bf16x8 __attribute__((ext_vector_type(8)));
typedef __bf16 bf16x4 __attribute__((ext_vector_type(4)));
typedef unsigned int u32;
typedef unsigned int u32x4 __attribute__((ext_vector_type(4)));

// level tables (static in reference)
__constant__ int c_R[NLVL]   = {16,18,20,22,25,27,30,34,38,42,47,52,58,64,72,80};
__constant__ int c_off[NLVL] = {0,4096,9928,17928,28576,44201,63884,90884,130188,185060,259148,362971,503579,698691,960835,1334083};
__constant__ int c_czy[NLVL] = {4,5,5,6,7,7,8,9,10,11,12,13,15,16,18,20};   // ceil(R/4)  (4-row wave tiles)
__constant__ int c_cx[NLVL]  = {1,2,2,2,2,2,2,3,3,3,3,4,4,4,5,5};           // ceil(R/16) (x-tiles = z-chunks)
// wave-tiles ordered level 15 -> 0 (longest first); count[l] = 2*czy*cx*cx
__constant__ int c_base[17]  = {0,1000,1900,2412,2892,3308,3524,3722,3902,4064,4128,4184,4240,4288,4328,4368,4376};

// weight fragments: [level][kz(3)][pair(5)][lane(64)][8 bf16] = 240 KB
__device__ __align__(16) unsigned short g_bfrag[NLVL*3*5*64*8];

// ---------------------------------------------------------------------------
// Pack weights into MFMA A-operand fragments (weights-as-A, data-as-B).
// ---------------------------------------------------------------------------
__global__ void prep_bfrag(const float* __restrict__ wgt) {
    int tid = blockIdx.x * 256 + threadIdx.x;
    if (tid >= NLVL*3*5*64) return;
    int lane = tid & 63;
    int p    = (tid >> 6) % 5;
    int d    = (tid / (5*64)) % 3;
    int l    = tid / (3*5*64);
    int quad = lane >> 4, co = lane & 15;
    unsigned short v[8];
#pragma unroll
    for (int j = 0; j < 8; ++j) {
        int k   = quad*8 + j;
        int tip = k >> 4;
        int ci  = k & 15;
        int t2  = 2*p + tip;
        float f = (t2 < 9) ? wgt[((l*27 + d*9 + t2)*16 + ci)*16 + co] : 0.f;
        v[j] = __builtin_bit_cast(unsigned short, (__bf16)f);
    }
    u32x4 pk;
    pk[0] = (u32)v[0] | ((u32)v[1] << 16);
    pk[1] = (u32)v[2] | ((u32)v[3] << 16);
    pk[2] = (u32)v[4] | ((u32)v[5] << 16);
    pk[3] = (u32)v[6] | ((u32)v[7] << 16);
    *(u32x4*)&g_bfrag[(size_t)tid*8] = pk;
}

__device__ __forceinline__ f32x4 bload(__amdgpu_buffer_rsrc_t rsrc, u32 voff) {
    u32x4 r = __builtin_amdgcn_raw_buffer_load_b128(rsrc, (int)voff, 0, 0);
    return __builtin_bit_cast(f32x4, r);
}

// ---------------------------------------------------------------------------
// Barrier-free streaming-z conv, z-unrolled x2, SRSRC buffer-load staging.
// Each WAVE owns a 16x * 4y tile streaming a 16-deep z-chunk. Per body:
// 14 buffer_load_dwordx4 (2 planes; halo/OOB lanes -> hardware-zero via
// num_records bounds check), 40 ds_read_b128, 120 MFMA into a rolling acc
// trio advanced twice (period-3 renaming, 3-body unroll), cvt+ds_write the
// 2 loaded planes into a 4-buffer LDS ring (rdsel ^= 8192). Buffer loads are
// vmcnt-only => fully decoupled from the lgkm ds_read->MFMA path.
// ---------------------------------------------------------------------------
__global__ __launch_bounds__(256, 2)
void conv_kernel(const float* __restrict__ in,
                 const float* __restrict__ bias,
                 float* __restrict__ out) {
    // per-wave 16KB: 4 bf16 plane buffers [yp 0..5][xp 0..17][ci 0..15] @ +0/+4096/+8192/+12288
    __shared__ __align__(16) char slab[4*16384];

    const int t    = threadIdx.x;
    const int lane = t & 63;
    const int wv   = t >> 6;

    // bijective XCD-aware swizzle (m204 variant, NBLOCK % 8 != 0)
    int bswz;
    {
        const int q = NBLOCK / 8, r = NBLOCK % 8;
        int xcd = blockIdx.x % 8, i = blockIdx.x / 8;
        bswz = (xcd < r ? xcd * (q + 1) : r * (q + 1) + (xcd - r) * q) + i;
    }

    const int tid4 = bswz*4 + wv;
    int idx = 0;
#pragma unroll
    for (int i = 1; i < 16; ++i) if (tid4 >= c_base[i]) idx = i;
    const int l = 15 - idx;
    const int R = c_R[l], off = c_off[l], czy = c_czy[l], cx = c_cx[l];

    int local = tid4 - c_base[idx];
    int per_b = czy*cx*cx;
    int bb = local / per_b;         int r1 = local - bb*per_b;
    int zt = r1 / (czy*cx);         int r2 = r1 - zt*(czy*cx);
    int yt = r2 / cx;               int xt = r2 - yt*cx;
    const int z0 = zt*16;
    const int z1 = (z0 + 16 < R) ? z0 + 16 : R;
    const int y0 = yt*4, x0 = xt*16;

    const int quad = lane >> 4;
    const int m    = lane & 15;
    const int qh   = quad >> 1;

    // ---- input SRSRC: base=in, stride=0, num_records=INBYTES, raw dword access ----
    __amdgpu_buffer_rsrc_t rsrc =
        __builtin_amdgcn_make_buffer_rsrc((void*)in, (short)0, INBYTES, 0x00020000);

    // ---- weight fragments resident (15 x 16B per lane) ----
    bf16x8 bfr[15];
#pragma unroll
    for (int d = 0; d < 3; ++d)
#pragma unroll
        for (int p = 0; p < 5; ++p)
            bfr[d*5+p] = *(const bf16x8*)&g_bfrag[(size_t)(((l*3 + d)*5 + p)*64 + lane)*8];

    // ---- A-frag LDS base pointers (5 pairs; rdsel/+4096/r*576 folded at use) ----
    const char* sbase = (const char*)slab + wv*16384;
    const char* arA[5];
    {
        const int T0[5] = {0, 64, 608, 1152, 1216};
        const int T1[5] = {32, 576, 640, 1184, 1216};
        const int ab = m*32 + (quad & 1)*16;
#pragma unroll
        for (int p = 0; p < 5; ++p) arA[p] = sbase + ab + (qh ? T1[p] : T0[p]);
    }
    char* wb = (char*)slab + wv*16384 + lane*8;

    // ---- staging voffsets: plane = 432 f32x4 chunks; slot s = chunk lane+s*64
    //      halo/OOB lanes parked at 0xC0000000 (hardware-zero, inc keeps OOB) ----
    const int  zsE = R*R*16;            // f32 elements per z-plane
    const u32  zsB = (u32)zsE*4;        // bytes per z-plane
    const long gstartE = ((long)bb*NTOT + off)*16;

    u32 cur[7];
#pragma unroll
    for (int s = 0; s < 7; ++s) {
        int c = lane + s*64;
        int yp = c/72; int rem = c - yp*72; int xp = rem>>2; int ci4 = (rem&3)<<2;
        int y = y0 + yp - 1, x = x0 + xp - 1;
        bool ok = (c < 432) && ((unsigned)y < (unsigned)R) && ((unsigned)x < (unsigned)R);
        long e = gstartE + (long)(z0-1)*zsE + ((long)y*R + x)*16 + ci4;
        cur[s] = ok ? (u32)(e*4) : 0xC0000000u;
    }

    const f32x4 z4 = {0,0,0,0};

    // ---- prologue: planes z0-1, z0 -> buffers 0, 1 ----
    {
        f32x4 L0[7], L1[7];
        const bool zok0 = (z0 > 0);
#pragma unroll
        for (int s = 0; s < 7; ++s) {
            u32 v0 = zok0 ? cur[s] : 0xC0000000u;
            L0[s] = bload(rsrc, v0);
            L1[s] = bload(rsrc, cur[s] + zsB);
        }
#pragma unroll
        for (int s = 0; s < 7; ++s) cur[s] += 2*zsB;
#pragma unroll
        for (int s = 0; s < 7; ++s) {
            bf16x4 h0 = {(__bf16)L0[s][0],(__bf16)L0[s][1],(__bf16)L0[s][2],(__bf16)L0[s][3]};
            *(bf16x4*)(wb + s*512) = h0;
            bf16x4 h1 = {(__bf16)L1[s][0],(__bf16)L1[s][1],(__bf16)L1[s][2],(__bf16)L1[s][3]};
            *(bf16x4*)(wb + 4096 + s*512) = h1;
        }
    }

    const bool xok = (x0 + m) < R;
    bool gr[4];
#pragma unroll
    for (int r = 0; r < 4; ++r) gr[r] = ((y0 + r) < R) && xok;
    const f32x4 bv4 = *(const f32x4*)(bias + (l << 4) + (quad << 2));

    float* so[4];
#pragma unroll
    for (int r = 0; r < 4; ++r)
        so[r] = out + gstartE + (((long)(z0-2)*R + (y0 + r))*(long)R + (x0 + m))*16 + (quad << 2);

    f32x4 c0[4], c1[4], c2[4];
#pragma unroll
    for (int r = 0; r < 4; ++r) { c0[r] = z4; c1[r] = z4; c2[r] = z4; }

    u32 rdsel = 0;
    int zl = z0 + 1;                    // first plane loaded by body 0
    int zq = z0 - 2;                    // out plane completed by body's plane-A MFMA
    const u32 zspan = (u32)(z1 - z0);   // stored outputs: [z0, z1)

    // Body: consumes planes (zq+1, zq+2) from LDS read-pair, loads planes
    // (zl, zl+1), stores outputs zq (from S) and zq+1 (from Q), writes loaded
    // planes to the other LDS pair. Trio renaming handled by caller rotation.
    auto body = [&](f32x4 (&P)[4], f32x4 (&Q)[4], f32x4 (&S)[4]) {
        // 1) issue 14 buffer loads (vmcnt-only, OOB -> zero)
        f32x4 LN[14];
        {
            const bool zA = (zl <= z1) && (zl < R);
            const bool zB = ((zl+1) <= z1) && ((zl+1) < R);
#pragma unroll
            for (int s = 0; s < 7; ++s) {
                u32 vA = zA ? cur[s] : 0xC0000000u;
                u32 vB = zB ? (cur[s] + zsB) : 0xC0000000u;
                LN[s]   = bload(rsrc, vA);
                LN[7+s] = bload(rsrc, vB);
            }
#pragma unroll
            for (int s = 0; s < 7; ++s) cur[s] += 2*zsB;
            zl += 2;
        }
        // 2) MFMA plane A (kz0->P=out zA+1, kz1->Q=out zA, kz2->S=out zA-1)
#pragma unroll
        for (int p = 0; p < 5; ++p) {
#pragma unroll
            for (int r = 0; r < 4; ++r) {
                bf16x8 af = *(const bf16x8*)(arA[p] + rdsel + r*576);
                P[r] = __builtin_amdgcn_mfma_f32_16x16x32_bf16(bfr[p],    af, P[r], 0,0,0);
                Q[r] = __builtin_amdgcn_mfma_f32_16x16x32_bf16(bfr[5+p],  af, Q[r], 0,0,0);
                S[r] = __builtin_amdgcn_mfma_f32_16x16x32_bf16(bfr[10+p], af, S[r], 0,0,0);
            }
        }
        // 3) store S = out zq; recycle S as fresh acc for out zB+1
        if ((u32)(zq - z0) < zspan) {
#pragma unroll
            for (int r = 0; r < 4; ++r)
                if (gr[r]) { f32x4 o = S[r] + bv4; __builtin_nontemporal_store(o, (f32x4*)so[r]); }
        }
#pragma unroll
        for (int r = 0; r < 4; ++r) S[r] = z4;
        // 4) MFMA plane B (kz1->P=out zB, kz2->Q=out zA, kz0->S=out zB+1)
#pragma unroll
        for (int p = 0; p < 5; ++p) {
#pragma unroll
            for (int r = 0; r < 4; ++r) {
                bf16x8 af = *(const bf16x8*)(arA[p] + rdsel + 4096 + r*576);
                P[r] = __builtin_amdgcn_mfma_f32_16x16x32_bf16(bfr[5+p],  af, P[r], 0,0,0);
                Q[r] = __builtin_amdgcn_mfma_f32_16x16x32_bf16(bfr[10+p], af, Q[r], 0,0,0);
                S[r] = __builtin_amdgcn_mfma_f32_16x16x32_bf16(bfr[p],    af, S[r], 0,0,0);
            }
        }
        // 5) store Q = out zq+1; recycle Q (becomes next body's fresh P)
        if ((u32)(zq + 1 - z0) < zspan) {
#pragma unroll
            for (int r = 0; r < 4; ++r)
                if (gr[r]) { f32x4 o = Q[r] + bv4; __builtin_nontemporal_store(o, (f32x4*)(so[r] + zsE)); }
        }
#pragma unroll
        for (int r = 0; r < 4; ++r) Q[r] = z4;
        // 6) cvt + write the 2 loaded planes to the other LDS pair
        {
            const u32 wsel = rdsel ^ 8192u;
#pragma unroll
            for (int s = 0; s < 7; ++s) {
                bf16x4 h0 = {(__bf16)LN[s][0],(__bf16)LN[s][1],(__bf16)LN[s][2],(__bf16)LN[s][3]};
                *(bf16x4*)(wb + wsel + s*512) = h0;
                bf16x4 h1 = {(__bf16)LN[7+s][0],(__bf16)LN[7+s][1],(__bf16)LN[7+s][2],(__bf16)LN[7+s][3]};
                *(bf16x4*)(wb + wsel + 4096 + s*512) = h1;
            }
            rdsel = wsel;
        }
#pragma unroll
        for (int r = 0; r < 4; ++r) so[r] += 2*(long)zsE;
        zq += 2;
    };

    const int nb = (z1 - z0 + 3) >> 1;   // ceil((z1-z0+2)/2) bodies
#pragma unroll 1
    for (int i = 0; i < nb; i += 3) {
        body(c0, c1, c2);
        body(c1, c2, c0);
        body(c2, c0, c1);
    }
}

extern "C" void kernel_launch(void* const* d_in, const int* in_sizes, int n_in,
                              void* d_out, int out_size, void* d_ws, size_t ws_size,
                              hipStream_t stream) {
    const float* inp = (const float*)d_in[0];
    const float* wgt = (const float*)d_in[1];
    const float* bia = (const float*)d_in[2];
    float* out = (float*)d_out;
    prep_bfrag<<<dim3((NLVL*3*5*64 + 255)/256), dim3(256), 0, stream>>>(wgt);
    conv_kernel<<<dim3(NBLOCK), dim3(256), 0, stream>>>(inp, bia, out);
}